// Round 7
// baseline (354.028 us; speedup 1.0000x reference)
//
#include <hip/hip_runtime.h>

// ---------------------------------------------------------------------------
// network_49581102465567: 5-layer linear MLP, codebook quantize after layer 2.
// Linear folds: Wa = w2@w1 [512x1024], Wc = (w5@w4)@w3 [512x512].
// Round 12: row-local fusion of gemmQ+gemmout. out[m,:] depends only on
// q[m,:], so a block computes 64 rows of h2 (ALL 512 cols, k-outer with
// acc[8][2][2] = 128 VGPR), quantizes into LDS qs[64][512], then runs the
// second GEMM from LDS. q never hits global (kills 16MB write + ~128MB
// re-read + one dispatch). Phase1: 32 fat steps (32 MFMA : 18 ds_reads per
// wave) with counted-vmcnt(9) dbuf pipeline (R10's proven skeleton incl.
// lgkmcnt(0) race fix). Phase2: WcT 64-row panel staged once per n-tile,
// 8 barrier-free K-steps from LDS. All LDS layouts XOR-chunk-swizzled so
// every fragment read is 2-way (free). Accumulation order per output
// element unchanged -> bit-identical (absmax 0.005981445).
// Dispatches: prep -> foldA{fold1,fold2,ba} -> foldB2{fold3,bc} -> fusedQO.
// ---------------------------------------------------------------------------

typedef __bf16 v8bf __attribute__((ext_vector_type(8)));
typedef float  v4f  __attribute__((ext_vector_type(4)));

#define Bdim   16384
#define DIN    1024
#define DOUT   512
#define H1dim  4096
#define H3dim  2048
#define H4dim  2048

#define GLOBAL_AS __attribute__((address_space(1)))
#define LDS_AS    __attribute__((address_space(3)))

__device__ __forceinline__ void load16_to_lds(const __bf16* g, __bf16* l) {
  __builtin_amdgcn_global_load_lds((const GLOBAL_AS unsigned int*)g,
                                   (LDS_AS unsigned int*)l, 16, 0, 0);
}

__device__ __forceinline__ unsigned pack2bf(float a, float b) {
  return (unsigned)__builtin_bit_cast(unsigned short, (__bf16)a) |
         ((unsigned)__builtin_bit_cast(unsigned short, (__bf16)b) << 16);
}

// ---- prep: transposes (64 in-rows x 32 in-cols -> 128 B writes) + casts ----
__device__ __forceinline__ void transpose_body(const float* __restrict__ in,
                                               __bf16* __restrict__ out,
                                               int R, int C, int bx, int by,
                                               float (*tile)[68]) {
  const int c0 = bx * 32, r0 = by * 64;
  const int t = threadIdx.x, tr = t >> 5, tc = t & 31;
#pragma unroll
  for (int i = 0; i < 8; ++i)
    tile[tc][tr + i * 8] = in[(size_t)(r0 + tr + i * 8) * C + (c0 + tc)];
  __syncthreads();
  const int orow = t >> 3, oc = (t & 7) * 8;      // 32 out-rows x 64 out-cols
  float4 a = *(const float4*)&tile[orow][oc];
  float4 b = *(const float4*)&tile[orow][oc + 4];
  int4 o;
  o.x = pack2bf(a.x, a.y); o.y = pack2bf(a.z, a.w);
  o.z = pack2bf(b.x, b.y); o.w = pack2bf(b.z, b.w);
  *(int4*)&out[(size_t)(c0 + orow) * R + (r0 + oc)] = o;
}

__device__ __forceinline__ void cast_body(const float* __restrict__ in,
                                          __bf16* __restrict__ out, int b) {
  const size_t i = (size_t)b * 2048 + (size_t)threadIdx.x * 8;
  float4 a = *(const float4*)&in[i];
  float4 c = *(const float4*)&in[i + 4];
  int4 o;
  o.x = pack2bf(a.x, a.y); o.y = pack2bf(a.z, a.w);
  o.z = pack2bf(c.x, c.y); o.w = pack2bf(c.z, c.w);
  *(int4*)&out[i] = o;
}

__global__ void prep_kernel(const float* __restrict__ w1, __bf16* __restrict__ w1T,
                            const float* __restrict__ w4, __bf16* __restrict__ w4T,
                            const float* __restrict__ w3, __bf16* __restrict__ w3T,
                            const float* __restrict__ x, __bf16* __restrict__ xb,
                            const float* __restrict__ w2, __bf16* __restrict__ w2b,
                            const float* __restrict__ w5, __bf16* __restrict__ w5b) {
  __shared__ float tile[32][68];
  int b = blockIdx.x;
  if (b < 2048) {                 // w1 [4096][1024] -> w1T [1024][4096]
    transpose_body(w1, w1T, H1dim, DIN, b & 31, b >> 5, tile);
  } else if (b < 4096) {          // w4 [2048][2048] -> w4T [2048][2048]
    b -= 2048;
    transpose_body(w4, w4T, H4dim, H3dim, b & 63, b >> 6, tile);
  } else if (b < 4608) {          // w3 [2048][512] -> w3T [512][2048]
    b -= 4096;
    transpose_body(w3, w3T, H3dim, DOUT, b & 15, b >> 4, tile);
  } else if (b < 12800) {         // x fp32 -> bf16 (16.8M elems)
    cast_body(x, xb, b - 4608);
  } else if (b < 13824) {         // w2 -> bf16 (2M elems)
    cast_body(w2, w2b, b - 12800);
  } else {                        // w5 -> bf16 (1M elems)
    cast_body(w5, w5b, b - 13824);
  }
}

// ---- folded bias bodies (identical math to R11) ----
__device__ __forceinline__ void bias_ba_body(int bb, const float* __restrict__ b1,
                                             const float* __restrict__ w2,
                                             const float* __restrict__ b2,
                                             float* __restrict__ ba) {
  const int wave = threadIdx.x >> 6, lane = threadIdx.x & 63;
  const int j = bb * 4 + wave;
  float s = 0.f;
  for (int k = lane; k < H1dim; k += 64) s += b1[k] * w2[(size_t)j * H1dim + k];
#pragma unroll
  for (int off = 32; off; off >>= 1) s += __shfl_xor(s, off, 64);
  if (lane == 0) ba[j] = s + b2[j];
}

__device__ __forceinline__ void bias_bc_body(int bb, const float* __restrict__ b3,
                                             const __bf16* __restrict__ WtT,
                                             const float* __restrict__ b4,
                                             const float* __restrict__ w5,
                                             const float* __restrict__ b5,
                                             float* __restrict__ bc) {
  const int wave = threadIdx.x >> 6, lane = threadIdx.x & 63;
  const int j = bb * 4 + wave;
  float s = 0.f;
  for (int k = lane; k < H4dim; k += 64)
    s += b3[k] * (float)WtT[(size_t)j * H4dim + k] + b4[k] * w5[(size_t)j * H4dim + k];
#pragma unroll
  for (int off = 32; off; off >>= 1) s += __shfl_xor(s, off, 64);
  if (lane == 0) bc[j] = s + b5[j];
}

// ---- fold GEMM body: 64x64 tile, BK=64, counted-vmcnt pipeline (R10) ----
enum { MODE_W = 0 };

#define ASM_BAR() asm volatile("s_barrier" ::: "memory")

template <int MODE, int BM>
__device__ __forceinline__ void gemm_body(__bf16* As, __bf16* Bs,
                                          int bx, int by,
                                          const __bf16* __restrict__ A,
                                          const __bf16* __restrict__ Bt,
                                          void* __restrict__ Cout,
                                          int M, int N, int K, int CH) {
  const int t = threadIdx.x;
  const int m0 = bx * BM, n0 = by * 64;
  const int lane = t & 63, wave = t >> 6;
  const int quad = lane >> 4, l15 = lane & 15;
  constexpr int MI = BM / 32;
  const int wm = (wave & 1) * (BM / 2), wn = (wave >> 1) * 32;

  const int lrow = lane >> 3;
  const int gcol = ((lane & 7) ^ lrow) * 8;
  const __bf16* gA = A  + (size_t)(m0 + (BM / 4) * wave + lrow) * K + gcol;
  const __bf16* gB = Bt + (size_t)(n0 + 16 * wave + lrow) * K + gcol;
  const int swz = l15 & 7;

  v4f acc[MI][2], accT[MI][2];
#pragma unroll
  for (int i = 0; i < MI; ++i)
#pragma unroll
    for (int j = 0; j < 2; ++j) {
      acc[i][j] = (v4f){0.f, 0.f, 0.f, 0.f};
      accT[i][j] = (v4f){0.f, 0.f, 0.f, 0.f};
    }

  auto stage = [&](int k0, int buf) {
    __bf16* lA = As + buf * (BM * 64) + (BM / 4) * wave * 64;
    __bf16* lB = Bs + buf * (64 * 64) + 16 * wave * 64;
#pragma unroll
    for (int p = 0; p < MI; ++p)
      load16_to_lds(gA + (size_t)(8 * p) * K + k0, lA + p * 512);
#pragma unroll
    for (int p = 0; p < 2; ++p)
      load16_to_lds(gB + (size_t)(8 * p) * K + k0, lB + p * 512);
  };

  const int nk = K >> 6;
  const int chsteps = CH >> 6;
  stage(0, 0);
  stage(64, 1);

  int cc = 0;
  for (int tk = 0; tk < nk; ++tk) {
    if (tk + 1 < nk) asm volatile("s_waitcnt vmcnt(4)" ::: "memory");
    else             asm volatile("s_waitcnt vmcnt(0)" ::: "memory");
    ASM_BAR();

    const __bf16* cA = As + (tk & 1) * (BM * 64);
    const __bf16* cB = Bs + (tk & 1) * (64 * 64);
#pragma unroll
    for (int kk = 0; kk < 2; ++kk) {
      const int cch = ((kk * 4 + quad) ^ swz) * 8;
      v8bf af[MI], bv[2];
#pragma unroll
      for (int i = 0; i < MI; ++i)
        af[i] = *(const v8bf*)&cA[(wm + i * 16 + l15) * 64 + cch];
#pragma unroll
      for (int j = 0; j < 2; ++j)
        bv[j] = *(const v8bf*)&cB[(wn + j * 16 + l15) * 64 + cch];
#pragma unroll
      for (int i = 0; i < MI; ++i)
#pragma unroll
        for (int j = 0; j < 2; ++j)
          acc[i][j] = __builtin_amdgcn_mfma_f32_16x16x32_bf16(af[i], bv[j], acc[i][j], 0, 0, 0);
    }
    if (++cc == chsteps) {          // chunk boundary: accT += chunk (left fold)
      cc = 0;
#pragma unroll
      for (int i = 0; i < MI; ++i)
#pragma unroll
        for (int j = 0; j < 2; ++j) {
          accT[i][j] += acc[i][j];
          acc[i][j] = (v4f){0.f, 0.f, 0.f, 0.f};
        }
    }
    asm volatile("s_waitcnt lgkmcnt(0)" ::: "memory");
    ASM_BAR();
    if (tk + 2 < nk) stage((tk + 2) << 6, tk & 1);
  }

#pragma unroll
  for (int j = 0; j < 2; ++j) {
    const int gn = n0 + wn + j * 16 + l15;
#pragma unroll
    for (int i = 0; i < MI; ++i)
#pragma unroll
      for (int r2 = 0; r2 < 4; ++r2) {
        const int gm = m0 + wm + i * 16 + quad * 4 + r2;
        ((__bf16*)Cout)[(size_t)gm * N + gn] = (__bf16)accT[i][j][r2];
      }
  }
}

// ---- dispatch A: fold1 (128 blk) + fold2 (256 blk) + ba (128 blk) ----
__global__ __launch_bounds__(256, 3)
void foldA_kernel(const __bf16* __restrict__ w2b, const __bf16* __restrict__ w1T,
                  __bf16* __restrict__ WaT,
                  const __bf16* __restrict__ w5b, const __bf16* __restrict__ w4T,
                  __bf16* __restrict__ WtT,
                  const float* __restrict__ b1, const float* __restrict__ w2,
                  const float* __restrict__ b2, float* __restrict__ ba) {
  __shared__ __align__(16) __bf16 As[2 * 64 * 64];
  __shared__ __align__(16) __bf16 Bs[2 * 64 * 64];
  int b = blockIdx.x;
  if (b < 128) {        // Wa = w2@w1: M=512, N=1024, K=4096, CH=512
    const int c = b & 7, i = b >> 3;
    gemm_body<MODE_W, 64>(As, Bs, i >> 1, c * 2 + (i & 1), w2b, w1T, WaT,
                          DOUT, DIN, H1dim, 512);
  } else if (b < 384) { // Wt = w5@w4: M=512, N=2048, K=2048, CH=512
    b -= 128;
    const int c = b & 7, i = b >> 3;
    gemm_body<MODE_W, 64>(As, Bs, i >> 2, c * 4 + (i & 3), w5b, w4T, WtT,
                          DOUT, H3dim, H4dim, 512);
  } else {              // ba
    bias_ba_body(b - 384, b1, w2, b2, ba);
  }
}

// ---- dispatch B2: fold3 (64 blk) + bc (128 blk) ----
__global__ __launch_bounds__(256, 3)
void foldB2_kernel(const __bf16* __restrict__ WtT, const __bf16* __restrict__ w3T,
                   __bf16* __restrict__ WcT,
                   const float* __restrict__ b3, const float* __restrict__ b4,
                   const float* __restrict__ w5, const float* __restrict__ b5,
                   float* __restrict__ bc) {
  __shared__ __align__(16) __bf16 As[2 * 64 * 64];
  __shared__ __align__(16) __bf16 Bs[2 * 64 * 64];
  int b = blockIdx.x;
  if (b < 64) {         // Wc = Wt@w3: M=512, N=512, K=2048, CH=256
    const int c = b & 7, i = b >> 3;
    gemm_body<MODE_W, 64>(As, Bs, i, c, WtT, w3T, WcT, DOUT, DOUT, H3dim, 256);
  } else {              // bc (needs WtT)
    bias_bc_body(b - 64, b3, WtT, b4, w5, b5, bc);
  }
}

// ---- fused gemmQ + gemmout: 64 rows/block, q lives in LDS only ----
// Phase 1 (k-outer, all 8 n-tiles resident): h2 = xb@WaT + ba -> quantize
//   -> qs[64][512]. B-panel [512][32k] dbuf, counted vmcnt(9); A [64][32k]
//   dbuf. Per step per wave: 32 MFMA vs 18 ds_reads.
// Phase 2: out = qs@WcT + bc. WcT 64-row panel staged once per n-tile,
//   then 16 barrier-free LDS K-steps.
// Swizzles (all reads 2-way): 32k-tiles (4 chunks): pos = chunk ^
//   ((row>>1)&3); 64-col tiles of qs/Bpanel (8 chunks): pos = chunk ^ (row&7).
__global__ __launch_bounds__(256, 1)
void fused_qo_kernel(const __bf16* __restrict__ xb, const __bf16* __restrict__ WaT,
                     const __bf16* __restrict__ WcT,
                     const float* __restrict__ ba, const float* __restrict__ bc,
                     const float* __restrict__ cb, float* __restrict__ out) {
  __shared__ __align__(16) __bf16 qs[64 * 512];      // 64 KB
  __shared__ __align__(16) __bf16 Bb[2 * 512 * 32];  // 64 KB (ph1 dbuf / ph2 panel)
  __shared__ __align__(16) __bf16 Ab[2 * 64 * 32];   // 8 KB
  __shared__ float cbs[256];

  const int t = threadIdx.x, lane = t & 63, wave = t >> 6;
  const int quad = lane >> 4, l15 = lane & 15;
  const int m0 = blockIdx.x * 64;
  cbs[t] = cb[t];

  const int wm = (wave & 1) * 32, wn = (wave >> 1) * 32;

  // ---------------- phase 1 ----------------
  // DMA source col within 32-k tile, pre-swizzled: chunk_g = (l&3)^((l>>3)&3)
  // (matches per-lane staged-row key ((row>>1)&3) for both A and B layouts).
  const int scol = ((lane & 3) ^ ((lane >> 3) & 3)) * 8;
  const __bf16* gA = xb  + (size_t)(m0 + 16 * wave + (lane >> 2)) * 1024 + scol;
  const __bf16* gB = WaT + (size_t)(128 * wave + (lane >> 2)) * 1024 + scol;

  auto stage1 = [&](int k0, int buf) {               // 9 loads per wave
    load16_to_lds(gA + k0, Ab + buf * 2048 + wave * 512);
#pragma unroll
    for (int p = 0; p < 8; ++p)
      load16_to_lds(gB + (size_t)p * 16384 + k0, Bb + buf * 16384 + wave * 4096 + p * 512);
  };

  v4f acc[8][2][2];
#pragma unroll
  for (int jn = 0; jn < 8; ++jn)
#pragma unroll
    for (int i = 0; i < 2; ++i)
#pragma unroll
      for (int j = 0; j < 2; ++j) acc[jn][i][j] = (v4f){0.f, 0.f, 0.f, 0.f};

  stage1(0, 0);
  stage1(32, 1);

  const int rk = (l15 >> 1) & 3;                     // read-side XOR key
  for (int ks = 0; ks < 32; ++ks) {
    if (ks + 1 < 32) asm volatile("s_waitcnt vmcnt(9)" ::: "memory");
    else             asm volatile("s_waitcnt vmcnt(0)" ::: "memory");
    ASM_BAR();

    const __bf16* cA = Ab + (ks & 1) * 2048;
    const __bf16* cB = Bb + (ks & 1) * 16384;
    const int cch = (quad ^ rk) * 8;
    v8bf af0 = *(const v8bf*)&cA[(wm +  0 + l15) * 32 + cch];
    v8bf af1 = *(const v8bf*)&cA[(wm + 16 + l15) * 32 + cch];
#pragma unroll
    for (int jn = 0; jn < 8; ++jn) {
      v8bf bv0 = *(const v8bf*)&cB[(jn * 64 + wn +  0 + l15) * 32 + cch];
      v8bf bv1 = *(const v8bf*)&cB[(jn * 64 + wn + 16 + l15) * 32 + cch];
      acc[jn][0][0] = __builtin_amdgcn_mfma_f32_16x16x32_bf16(af0, bv0, acc[jn][0][0], 0, 0, 0);
      acc[jn][1][0] = __builtin_amdgcn_mfma_f32_16x16x32_bf16(af1, bv0, acc[jn][1][0], 0, 0, 0);
      acc[jn][0][1] = __builtin_amdgcn_mfma_f32_16x16x32_bf16(af0, bv1, acc[jn][0][1], 0, 0, 0);
      acc[jn][1][1] = __builtin_amdgcn_mfma_f32_16x16x32_bf16(af1, bv1, acc[jn][1][1], 0, 0, 0);
    }
    asm volatile("s_waitcnt lgkmcnt(0)" ::: "memory");   // R10 race fix
    ASM_BAR();
    if (ks + 2 < 32) stage1((ks + 2) * 32, ks & 1);
  }

  // epilogue: bias + quantize -> qs (swizzled by row&7 per 64-col tile)
#pragma unroll
  for (int jn = 0; jn < 8; ++jn) {
#pragma unroll
    for (int j = 0; j < 2; ++j) {
      const int cc = wn + j * 16 + l15;              // col within tile jn
      const float bj = ba[jn * 64 + cc];
#pragma unroll
      for (int i = 0; i < 2; ++i) {
#pragma unroll
        for (int r = 0; r < 4; ++r) {
          const int row = wm + i * 16 + quad * 4 + r;
          float v = acc[jn][i][j][r] + bj;
          int idx = 0;
#pragma unroll
          for (int s = 128; s > 0; s >>= 1) {
            const int u = idx + s;
            if (cbs[u] <= v) idx = u;
          }
          float best = cbs[idx];
          if (idx < 255) {
            const float c1 = cbs[idx + 1];
            if (!(v - best <= c1 - v)) best = c1;
          }
          qs[row * 512 + jn * 64 + (((cc >> 3) ^ (row & 7)) * 8) + (cc & 7)] = (__bf16)best;
        }
      }
    }
  }
  asm volatile("s_waitcnt lgkmcnt(0)" ::: "memory");
  ASM_BAR();

  // ---------------- phase 2 ----------------
#pragma unroll 1
  for (int jn2 = 0; jn2 < 8; ++jn2) {
    const int n02 = jn2 * 64;
    // stage WcT rows [n02, n02+64) -> Bb[64][512], chunk XOR'd by row&7
#pragma unroll
    for (int p = 0; p < 16; ++p) {
      const int row = 16 * wave + p;
      const int g = (lane >> 3) * 64 + (((lane & 7) ^ (p & 7)) * 8);
      load16_to_lds(WcT + (size_t)(n02 + row) * 512 + g, Bb + row * 512);
    }
    asm volatile("s_waitcnt vmcnt(0)" ::: "memory");
    ASM_BAR();

    v4f a2[2][2];
#pragma unroll
    for (int i = 0; i < 2; ++i)
#pragma unroll
      for (int j = 0; j < 2; ++j) a2[i][j] = (v4f){0.f, 0.f, 0.f, 0.f};

#pragma unroll
    for (int kt = 0; kt < 8; ++kt) {
#pragma unroll
      for (int kk = 0; kk < 2; ++kk) {
        const int pos = (((kk * 4 + quad) ^ (l15 & 7)) * 8);
        v8bf af0 = *(const v8bf*)&qs[(wm +  0 + l15) * 512 + kt * 64 + pos];
        v8bf af1 = *(const v8bf*)&qs[(wm + 16 + l15) * 512 + kt * 64 + pos];
        v8bf bv0 = *(const v8bf*)&Bb[(wn +  0 + l15) * 512 + kt * 64 + pos];
        v8bf bv1 = *(const v8bf*)&Bb[(wn + 16 + l15) * 512 + kt * 64 + pos];
        a2[0][0] = __builtin_amdgcn_mfma_f32_16x16x32_bf16(af0, bv0, a2[0][0], 0, 0, 0);
        a2[1][0] = __builtin_amdgcn_mfma_f32_16x16x32_bf16(af1, bv0, a2[1][0], 0, 0, 0);
        a2[0][1] = __builtin_amdgcn_mfma_f32_16x16x32_bf16(af0, bv1, a2[0][1], 0, 0, 0);
        a2[1][1] = __builtin_amdgcn_mfma_f32_16x16x32_bf16(af1, bv1, a2[1][1], 0, 0, 0);
      }
    }

#pragma unroll
    for (int j = 0; j < 2; ++j) {
      const int gn = n02 + wn + j * 16 + l15;
      const float bj = bc[gn];
#pragma unroll
      for (int i = 0; i < 2; ++i)
#pragma unroll
        for (int r = 0; r < 4; ++r)
          out[(size_t)(m0 + wm + i * 16 + quad * 4 + r) * 512 + gn] = a2[i][j][r] + bj;
    }
    asm volatile("s_waitcnt lgkmcnt(0)" ::: "memory");   // protect Bb reuse
    ASM_BAR();
  }
}

extern "C" void kernel_launch(void* const* d_in, const int* in_sizes, int n_in,
                              void* d_out, int out_size, void* d_ws, size_t ws_size,
                              hipStream_t stream) {
  const float* x  = (const float*)d_in[0];
  const float* cb = (const float*)d_in[1];
  const float* w1 = (const float*)d_in[2];   // [4096,1024]
  const float* b1 = (const float*)d_in[3];
  const float* w2 = (const float*)d_in[4];   // [512,4096]
  const float* b2 = (const float*)d_in[5];
  const float* w3 = (const float*)d_in[6];   // [2048,512]
  const float* b3 = (const float*)d_in[7];
  const float* w4 = (const float*)d_in[8];   // [2048,2048]
  const float* b4 = (const float*)d_in[9];
  const float* w5 = (const float*)d_in[10];  // [512,2048]
  const float* b5 = (const float*)d_in[11];
  float* out = (float*)d_out;

  char* ws = (char*)d_ws;
  size_t off = 0;
  auto alloc = [&](size_t bytes) -> void* {
    void* p = ws + off;
    off = (off + bytes + 255) & ~(size_t)255;
    return p;
  };
  __bf16* w1T = (__bf16*)alloc((size_t)DIN * H1dim * 2);     // 8 MB
  __bf16* w4T = (__bf16*)alloc((size_t)H3dim * H4dim * 2);   // 8 MB
  __bf16* w3T = (__bf16*)alloc((size_t)DOUT * H3dim * 2);    // 2 MB
  __bf16* w2b = (__bf16*)alloc((size_t)DOUT * H1dim * 2);    // 4 MB
  __bf16* w5b = (__bf16*)alloc((size_t)DOUT * H4dim * 2);    // 2 MB
  __bf16* WaT = (__bf16*)alloc((size_t)DOUT * DIN * 2);      // 1 MB
  __bf16* WtT = (__bf16*)alloc((size_t)DOUT * H3dim * 2);    // 2 MB
  __bf16* WcT = (__bf16*)alloc((size_t)DOUT * DOUT * 2);     // 0.5 MB
  __bf16* xb  = (__bf16*)alloc((size_t)Bdim * DIN * 2);      // 32 MB
  float*  ba  = (float*)alloc(DOUT * 4);
  float*  bc  = (float*)alloc(DOUT * 4);

  // 1) transposes (w1,w4,w3) + casts (x,w2,w5)
  prep_kernel<<<14336, 256, 0, stream>>>(w1, w1T, w4, w4T, w3, w3T,
                                         x, xb, w2, w2b, w5, w5b);

  // 2) fold1 + fold2 + ba
  foldA_kernel<<<512, 256, 0, stream>>>(w2b, w1T, WaT, w5b, w4T, WtT,
                                        b1, w2, b2, ba);

  // 3) fold3 + bc
  foldB2_kernel<<<192, 256, 0, stream>>>(WtT, w3T, WcT, b3, b4, w5, b5, bc);

  // 4) fused: h2 = xb@Wa + ba -> quantize (LDS) -> out = q@Wc + bc
  fused_qo_kernel<<<256, 256, 0, stream>>>(xb, WaT, WcT, ba, bc, cb, out);
}

// Round 8
// 273.660 us; speedup vs baseline: 1.2937x; 1.2937x over previous
//
#include <hip/hip_runtime.h>

// ---------------------------------------------------------------------------
// network_49581102465567: 5-layer linear MLP, codebook quantize after layer 2.
// Linear folds: Wa = w2@w1 [512x1024], Wc = (w5@w4)@w3 [512x512].
// Round 13: revert R12's fusion (1 blk/CU killed it); back to R11 structure.
// Change: gemmQ/gemmout move to 128x128 tiles (wave owns 64x64, acc=64VGPR):
// per K-step per wave 32 MFMA : 16 ds_reads : 8 DMA loads (2x fatter than
// R11's 16:12:6) while LDS=64KB dbuf keeps 2 blocks/CU (grid 512 = 2/CU).
// xb column-pass re-read drops 8x -> 4x. Same counted-vmcnt + lgkmcnt(0)
// skeleton (R10-verified), same XOR swizzle (row&7 == l15&7 still), same
// tk/kk-ascending K order -> bit-identical (absmax 0.005981445).
// Dispatches: prep -> foldA{fold1,fold2,ba} -> foldB{fold3,bc,gemmQ} ->
// gemmout. Fold bodies/remaps identical to R11.
// ---------------------------------------------------------------------------

typedef __bf16 v8bf __attribute__((ext_vector_type(8)));
typedef float  v4f  __attribute__((ext_vector_type(4)));

#define Bdim   16384
#define DIN    1024
#define DOUT   512
#define H1dim  4096
#define H3dim  2048
#define H4dim  2048

#define GLOBAL_AS __attribute__((address_space(1)))
#define LDS_AS    __attribute__((address_space(3)))

__device__ __forceinline__ void load16_to_lds(const __bf16* g, __bf16* l) {
  __builtin_amdgcn_global_load_lds((const GLOBAL_AS unsigned int*)g,
                                   (LDS_AS unsigned int*)l, 16, 0, 0);
}

__device__ __forceinline__ unsigned pack2bf(float a, float b) {
  return (unsigned)__builtin_bit_cast(unsigned short, (__bf16)a) |
         ((unsigned)__builtin_bit_cast(unsigned short, (__bf16)b) << 16);
}

// ---- prep: transposes (64 in-rows x 32 in-cols -> 128 B writes) + casts ----
__device__ __forceinline__ void transpose_body(const float* __restrict__ in,
                                               __bf16* __restrict__ out,
                                               int R, int C, int bx, int by,
                                               float (*tile)[68]) {
  const int c0 = bx * 32, r0 = by * 64;
  const int t = threadIdx.x, tr = t >> 5, tc = t & 31;
#pragma unroll
  for (int i = 0; i < 8; ++i)
    tile[tc][tr + i * 8] = in[(size_t)(r0 + tr + i * 8) * C + (c0 + tc)];
  __syncthreads();
  const int orow = t >> 3, oc = (t & 7) * 8;      // 32 out-rows x 64 out-cols
  float4 a = *(const float4*)&tile[orow][oc];
  float4 b = *(const float4*)&tile[orow][oc + 4];
  int4 o;
  o.x = pack2bf(a.x, a.y); o.y = pack2bf(a.z, a.w);
  o.z = pack2bf(b.x, b.y); o.w = pack2bf(b.z, b.w);
  *(int4*)&out[(size_t)(c0 + orow) * R + (r0 + oc)] = o;
}

__device__ __forceinline__ void cast_body(const float* __restrict__ in,
                                          __bf16* __restrict__ out, int b) {
  const size_t i = (size_t)b * 2048 + (size_t)threadIdx.x * 8;
  float4 a = *(const float4*)&in[i];
  float4 c = *(const float4*)&in[i + 4];
  int4 o;
  o.x = pack2bf(a.x, a.y); o.y = pack2bf(a.z, a.w);
  o.z = pack2bf(c.x, c.y); o.w = pack2bf(c.z, c.w);
  *(int4*)&out[i] = o;
}

__global__ void prep_kernel(const float* __restrict__ w1, __bf16* __restrict__ w1T,
                            const float* __restrict__ w4, __bf16* __restrict__ w4T,
                            const float* __restrict__ w3, __bf16* __restrict__ w3T,
                            const float* __restrict__ x, __bf16* __restrict__ xb,
                            const float* __restrict__ w2, __bf16* __restrict__ w2b,
                            const float* __restrict__ w5, __bf16* __restrict__ w5b) {
  __shared__ float tile[32][68];
  int b = blockIdx.x;
  if (b < 2048) {                 // w1 [4096][1024] -> w1T [1024][4096]
    transpose_body(w1, w1T, H1dim, DIN, b & 31, b >> 5, tile);
  } else if (b < 4096) {          // w4 [2048][2048] -> w4T [2048][2048]
    b -= 2048;
    transpose_body(w4, w4T, H4dim, H3dim, b & 63, b >> 6, tile);
  } else if (b < 4608) {          // w3 [2048][512] -> w3T [512][2048]
    b -= 4096;
    transpose_body(w3, w3T, H3dim, DOUT, b & 15, b >> 4, tile);
  } else if (b < 12800) {         // x fp32 -> bf16 (16.8M elems)
    cast_body(x, xb, b - 4608);
  } else if (b < 13824) {         // w2 -> bf16 (2M elems)
    cast_body(w2, w2b, b - 12800);
  } else {                        // w5 -> bf16 (1M elems)
    cast_body(w5, w5b, b - 13824);
  }
}

// ---- folded bias bodies (identical math to R11) ----
__device__ __forceinline__ void bias_ba_body(int bb, const float* __restrict__ b1,
                                             const float* __restrict__ w2,
                                             const float* __restrict__ b2,
                                             float* __restrict__ ba) {
  const int wave = threadIdx.x >> 6, lane = threadIdx.x & 63;
  const int j = bb * 4 + wave;
  float s = 0.f;
  for (int k = lane; k < H1dim; k += 64) s += b1[k] * w2[(size_t)j * H1dim + k];
#pragma unroll
  for (int off = 32; off; off >>= 1) s += __shfl_xor(s, off, 64);
  if (lane == 0) ba[j] = s + b2[j];
}

__device__ __forceinline__ void bias_bc_body(int bb, const float* __restrict__ b3,
                                             const __bf16* __restrict__ WtT,
                                             const float* __restrict__ b4,
                                             const float* __restrict__ w5,
                                             const float* __restrict__ b5,
                                             float* __restrict__ bc) {
  const int wave = threadIdx.x >> 6, lane = threadIdx.x & 63;
  const int j = bb * 4 + wave;
  float s = 0.f;
  for (int k = lane; k < H4dim; k += 64)
    s += b3[k] * (float)WtT[(size_t)j * H4dim + k] + b4[k] * w5[(size_t)j * H4dim + k];
#pragma unroll
  for (int off = 32; off; off >>= 1) s += __shfl_xor(s, off, 64);
  if (lane == 0) bc[j] = s + b5[j];
}

#define ASM_BAR() asm volatile("s_barrier" ::: "memory")

// ---- fold GEMM body: 64x64 tile, BK=64, counted-vmcnt pipeline (R11) ----
__device__ __forceinline__ void fold_body(__bf16* As, __bf16* Bs,
                                          int bx, int by,
                                          const __bf16* __restrict__ A,
                                          const __bf16* __restrict__ Bt,
                                          __bf16* __restrict__ Cout,
                                          int M, int N, int K, int CH) {
  const int t = threadIdx.x;
  const int m0 = bx * 64, n0 = by * 64;
  const int lane = t & 63, wave = t >> 6;
  const int quad = lane >> 4, l15 = lane & 15;
  const int wm = (wave & 1) * 32, wn = (wave >> 1) * 32;

  const int lrow = lane >> 3;
  const int gcol = ((lane & 7) ^ lrow) * 8;
  const __bf16* gA = A  + (size_t)(m0 + 16 * wave + lrow) * K + gcol;
  const __bf16* gB = Bt + (size_t)(n0 + 16 * wave + lrow) * K + gcol;
  const int swz = l15 & 7;

  v4f acc[2][2], accT[2][2];
#pragma unroll
  for (int i = 0; i < 2; ++i)
#pragma unroll
    for (int j = 0; j < 2; ++j) {
      acc[i][j] = (v4f){0.f, 0.f, 0.f, 0.f};
      accT[i][j] = (v4f){0.f, 0.f, 0.f, 0.f};
    }

  auto stage = [&](int k0, int buf) {              // 4 loads per wave
    __bf16* lA = As + buf * 4096 + 16 * wave * 64;
    __bf16* lB = Bs + buf * 4096 + 16 * wave * 64;
#pragma unroll
    for (int p = 0; p < 2; ++p)
      load16_to_lds(gA + (size_t)(8 * p) * K + k0, lA + p * 512);
#pragma unroll
    for (int p = 0; p < 2; ++p)
      load16_to_lds(gB + (size_t)(8 * p) * K + k0, lB + p * 512);
  };

  const int nk = K >> 6;
  const int chsteps = CH >> 6;
  stage(0, 0);
  stage(64, 1);

  int cc = 0;
  for (int tk = 0; tk < nk; ++tk) {
    if (tk + 1 < nk) asm volatile("s_waitcnt vmcnt(4)" ::: "memory");
    else             asm volatile("s_waitcnt vmcnt(0)" ::: "memory");
    ASM_BAR();

    const __bf16* cA = As + (tk & 1) * 4096;
    const __bf16* cB = Bs + (tk & 1) * 4096;
#pragma unroll
    for (int kk = 0; kk < 2; ++kk) {
      const int cch = ((kk * 4 + quad) ^ swz) * 8;
      v8bf af[2], bv[2];
#pragma unroll
      for (int i = 0; i < 2; ++i)
        af[i] = *(const v8bf*)&cA[(wm + i * 16 + l15) * 64 + cch];
#pragma unroll
      for (int j = 0; j < 2; ++j)
        bv[j] = *(const v8bf*)&cB[(wn + j * 16 + l15) * 64 + cch];
#pragma unroll
      for (int i = 0; i < 2; ++i)
#pragma unroll
        for (int j = 0; j < 2; ++j)
          acc[i][j] = __builtin_amdgcn_mfma_f32_16x16x32_bf16(af[i], bv[j], acc[i][j], 0, 0, 0);
    }
    if (++cc == chsteps) {          // chunk boundary: accT += chunk (left fold)
      cc = 0;
#pragma unroll
      for (int i = 0; i < 2; ++i)
#pragma unroll
        for (int j = 0; j < 2; ++j) {
          accT[i][j] += acc[i][j];
          acc[i][j] = (v4f){0.f, 0.f, 0.f, 0.f};
        }
    }
    asm volatile("s_waitcnt lgkmcnt(0)" ::: "memory");   // R10 race fix
    ASM_BAR();
    if (tk + 2 < nk) stage((tk + 2) << 6, tk & 1);
  }

#pragma unroll
  for (int j = 0; j < 2; ++j) {
    const int gn = n0 + wn + j * 16 + l15;
#pragma unroll
    for (int i = 0; i < 2; ++i)
#pragma unroll
      for (int r2 = 0; r2 < 4; ++r2) {
        const int gm = m0 + wm + i * 16 + quad * 4 + r2;
        Cout[(size_t)gm * N + gn] = (__bf16)accT[i][j][r2];
      }
  }
}

// ---- main GEMM body: 128x128 tile, BK=64, wave owns 64x64 ----
// Per K-step per wave: 32 MFMA : 16 ds_read_b128 : 8 global_load_lds.
// Same counted-vmcnt skeleton; LPS=8. Swizzle: row&7 == l15&7 (row offsets
// wm/wn multiples of 16). LDS 64KB dbuf -> 2 blocks/CU.
enum { MODE_Q = 1, MODE_OUT = 2 };

template <int MODE>
__device__ __forceinline__ void gemm128_body(__bf16* As, __bf16* Bs, float* cbs,
                                             int bx, int by,
                                             const __bf16* __restrict__ A,
                                             const __bf16* __restrict__ Bt,
                                             void* __restrict__ Cout,
                                             const float* __restrict__ bias,
                                             const float* __restrict__ codebook,
                                             int M, int N, int K) {
  const int t = threadIdx.x;
  const int m0 = bx * 128, n0 = by * 128;
  if constexpr (MODE == MODE_Q) cbs[t] = codebook[t];

  const int lane = t & 63, wave = t >> 6;
  const int quad = lane >> 4, l15 = lane & 15;
  const int wm = (wave & 1) * 64, wn = (wave >> 1) * 64;

  const int lrow = lane >> 3;
  const int gcol = ((lane & 7) ^ lrow) * 8;
  const __bf16* gA = A  + (size_t)(m0 + 32 * wave + lrow) * K + gcol;
  const __bf16* gB = Bt + (size_t)(n0 + 32 * wave + lrow) * K + gcol;
  const int swz = l15 & 7;

  v4f acc[4][4];
#pragma unroll
  for (int i = 0; i < 4; ++i)
#pragma unroll
    for (int j = 0; j < 4; ++j) acc[i][j] = (v4f){0.f, 0.f, 0.f, 0.f};

  auto stage = [&](int k0, int buf) {              // 8 loads per wave
    __bf16* lA = As + buf * 8192 + 32 * wave * 64;
    __bf16* lB = Bs + buf * 8192 + 32 * wave * 64;
#pragma unroll
    for (int p = 0; p < 4; ++p)
      load16_to_lds(gA + (size_t)(8 * p) * K + k0, lA + p * 512);
#pragma unroll
    for (int p = 0; p < 4; ++p)
      load16_to_lds(gB + (size_t)(8 * p) * K + k0, lB + p * 512);
  };

  const int nk = K >> 6;
  stage(0, 0);
  stage(64, 1);

  for (int tk = 0; tk < nk; ++tk) {
    if (tk + 1 < nk) asm volatile("s_waitcnt vmcnt(8)" ::: "memory");
    else             asm volatile("s_waitcnt vmcnt(0)" ::: "memory");
    ASM_BAR();

    const __bf16* cA = As + (tk & 1) * 8192;
    const __bf16* cB = Bs + (tk & 1) * 8192;
#pragma unroll
    for (int kk = 0; kk < 2; ++kk) {
      const int cch = ((kk * 4 + quad) ^ swz) * 8;
      v8bf af[4], bv[4];
#pragma unroll
      for (int i = 0; i < 4; ++i)
        af[i] = *(const v8bf*)&cA[(wm + i * 16 + l15) * 64 + cch];
#pragma unroll
      for (int j = 0; j < 4; ++j)
        bv[j] = *(const v8bf*)&cB[(wn + j * 16 + l15) * 64 + cch];
#pragma unroll
      for (int i = 0; i < 4; ++i)
#pragma unroll
        for (int j = 0; j < 4; ++j)
          acc[i][j] = __builtin_amdgcn_mfma_f32_16x16x32_bf16(af[i], bv[j], acc[i][j], 0, 0, 0);
    }
    asm volatile("s_waitcnt lgkmcnt(0)" ::: "memory");   // R10 race fix
    ASM_BAR();
    if (tk + 2 < nk) stage((tk + 2) << 6, tk & 1);
  }

#pragma unroll
  for (int j = 0; j < 4; ++j) {
    const int gn = n0 + wn + j * 16 + l15;
    const float bj = bias[gn];
#pragma unroll
    for (int i = 0; i < 4; ++i) {
#pragma unroll
      for (int r = 0; r < 4; ++r) {
        const int gm = m0 + wm + i * 16 + quad * 4 + r;
        float v = acc[i][j][r] + bj;
        if constexpr (MODE == MODE_Q) {
          int idx = 0;
#pragma unroll
          for (int s = 128; s > 0; s >>= 1) {
            const int u = idx + s;
            if (cbs[u] <= v) idx = u;
          }
          float best = cbs[idx];
          if (idx < 255) {
            const float c1 = cbs[idx + 1];
            if (!(v - best <= c1 - v)) best = c1;
          }
          ((__bf16*)Cout)[(size_t)gm * N + gn] = (__bf16)best;
        } else {
          ((float*)Cout)[(size_t)gm * N + gn] = v;
        }
      }
    }
  }
}

// ---- dispatch A: fold1 (128 blk) + fold2 (256 blk) + ba (128 blk) ----
__global__ __launch_bounds__(256, 3)
void foldA_kernel(const __bf16* __restrict__ w2b, const __bf16* __restrict__ w1T,
                  __bf16* __restrict__ WaT,
                  const __bf16* __restrict__ w5b, const __bf16* __restrict__ w4T,
                  __bf16* __restrict__ WtT,
                  const float* __restrict__ b1, const float* __restrict__ w2,
                  const float* __restrict__ b2, float* __restrict__ ba) {
  __shared__ __align__(16) __bf16 As[2 * 64 * 64];
  __shared__ __align__(16) __bf16 Bs[2 * 64 * 64];
  int b = blockIdx.x;
  if (b < 128) {        // Wa = w2@w1: M=512, N=1024, K=4096, CH=512
    const int c = b & 7, i = b >> 3;
    fold_body(As, Bs, i >> 1, c * 2 + (i & 1), w2b, w1T, WaT,
              DOUT, DIN, H1dim, 512);
  } else if (b < 384) { // Wt = w5@w4: M=512, N=2048, K=2048, CH=512
    b -= 128;
    const int c = b & 7, i = b >> 3;
    fold_body(As, Bs, i >> 2, c * 4 + (i & 3), w5b, w4T, WtT,
              DOUT, H3dim, H4dim, 512);
  } else {              // ba
    bias_ba_body(b - 384, b1, w2, b2, ba);
  }
}

// ---- dispatch B: fold3 (64) + bc (128) + gemmQ 128x128 (512) ----
__global__ __launch_bounds__(256, 2)
void foldB_kernel(const __bf16* __restrict__ WtT, const __bf16* __restrict__ w3T,
                  __bf16* __restrict__ WcT,
                  const float* __restrict__ b3, const float* __restrict__ b4,
                  const float* __restrict__ w5, const float* __restrict__ b5,
                  float* __restrict__ bc,
                  const __bf16* __restrict__ xb, const __bf16* __restrict__ WaT,
                  __bf16* __restrict__ q, const float* __restrict__ ba,
                  const float* __restrict__ cb) {
  __shared__ __align__(16) __bf16 As[2 * 128 * 64];   // 32 KB
  __shared__ __align__(16) __bf16 Bs[2 * 128 * 64];   // 32 KB
  __shared__ float cbs[256];
  int b = blockIdx.x;
  if (b < 64) {         // Wc = Wt@w3: M=512, N=512, K=2048, CH=256
    const int c = b & 7, i = b >> 3;
    fold_body(As, Bs, i, c, WtT, w3T, WcT, DOUT, DOUT, H3dim, 256);
  } else if (b < 192) { // bc (needs WtT)
    bias_bc_body(b - 64, b3, WtT, b4, w5, b5, bc);
  } else {              // h2 = xb@Wa + ba -> quantize -> q
    b -= 192;           // 192 % 8 == 0 -> XCD = b % 8 preserved
    // XCD c: 64 blocks = 16 A-panels x 4 n-tiles (panel-major within XCD)
    const int c = b & 7, i = b >> 3;
    gemm128_body<MODE_Q>(As, Bs, cbs, c * 16 + (i >> 2), i & 3, xb, WaT, q,
                         ba, cb, Bdim, DOUT, DIN);
  }
}

// ---- dispatch C: out = q@Wc + bc (128x128 tiles, 512 blocks) ----
__global__ __launch_bounds__(256, 2)
void gemmout_kernel(const __bf16* __restrict__ q, const __bf16* __restrict__ WcT,
                    float* __restrict__ out, const float* __restrict__ bc) {
  __shared__ __align__(16) __bf16 As[2 * 128 * 64];
  __shared__ __align__(16) __bf16 Bs[2 * 128 * 64];
  const int b = blockIdx.x;
  const int c = b & 7, i = b >> 3;              // same remap as gemmQ
  gemm128_body<MODE_OUT>(As, Bs, nullptr, c * 16 + (i >> 2), i & 3,
                         q, WcT, out, bc, nullptr, Bdim, DOUT, DOUT);
}

extern "C" void kernel_launch(void* const* d_in, const int* in_sizes, int n_in,
                              void* d_out, int out_size, void* d_ws, size_t ws_size,
                              hipStream_t stream) {
  const float* x  = (const float*)d_in[0];
  const float* cb = (const float*)d_in[1];
  const float* w1 = (const float*)d_in[2];   // [4096,1024]
  const float* b1 = (const float*)d_in[3];
  const float* w2 = (const float*)d_in[4];   // [512,4096]
  const float* b2 = (const float*)d_in[5];
  const float* w3 = (const float*)d_in[6];   // [2048,512]
  const float* b3 = (const float*)d_in[7];
  const float* w4 = (const float*)d_in[8];   // [2048,2048]
  const float* b4 = (const float*)d_in[9];
  const float* w5 = (const float*)d_in[10];  // [512,2048]
  const float* b5 = (const float*)d_in[11];
  float* out = (float*)d_out;

  char* ws = (char*)d_ws;
  size_t off = 0;
  auto alloc = [&](size_t bytes) -> void* {
    void* p = ws + off;
    off = (off + bytes + 255) & ~(size_t)255;
    return p;
  };
  __bf16* w1T = (__bf16*)alloc((size_t)DIN * H1dim * 2);     // 8 MB
  __bf16* w4T = (__bf16*)alloc((size_t)H3dim * H4dim * 2);   // 8 MB
  __bf16* w3T = (__bf16*)alloc((size_t)DOUT * H3dim * 2);    // 2 MB
  __bf16* w2b = (__bf16*)alloc((size_t)DOUT * H1dim * 2);    // 4 MB
  __bf16* w5b = (__bf16*)alloc((size_t)DOUT * H4dim * 2);    // 2 MB
  __bf16* WaT = (__bf16*)alloc((size_t)DOUT * DIN * 2);      // 1 MB
  __bf16* WtT = (__bf16*)alloc((size_t)DOUT * H3dim * 2);    // 2 MB
  __bf16* WcT = (__bf16*)alloc((size_t)DOUT * DOUT * 2);     // 0.5 MB
  __bf16* q   = (__bf16*)alloc((size_t)Bdim * DOUT * 2);     // 16 MB
  __bf16* xb  = (__bf16*)alloc((size_t)Bdim * DIN * 2);      // 32 MB
  float*  ba  = (float*)alloc(DOUT * 4);
  float*  bc  = (float*)alloc(DOUT * 4);

  // 1) transposes (w1,w4,w3) + casts (x,w2,w5)
  prep_kernel<<<14336, 256, 0, stream>>>(w1, w1T, w4, w4T, w3, w3T,
                                         x, xb, w2, w2b, w5, w5b);

  // 2) fold1 + fold2 + ba
  foldA_kernel<<<512, 256, 0, stream>>>(w2b, w1T, WaT, w5b, w4T, WtT,
                                        b1, w2, b2, ba);

  // 3) fold3 + bc + gemmQ (128x128)
  foldB_kernel<<<704, 256, 0, stream>>>(WtT, w3T, WcT, b3, b4, w5, b5, bc,
                                        xb, WaT, q, ba, cb);

  // 4) out = q@Wc + bc (128x128)
  gemmout_kernel<<<512, 256, 0, stream>>>(q, WcT, out, bc);
}